// Round 5
// baseline (504.969 us; speedup 1.0000x reference)
//
#include <hip/hip_runtime.h>
#include <math.h>

#define NCH 192
#define NB 8
#define SPAT 32768                        // 32^3
#define TILES_ALL 512                     // 64-pos tiles per sample
#define NELEM_PER_B ((size_t)NCH * SPAT)  // 6291456

typedef short s16x8 __attribute__((ext_vector_type(8)));
typedef float f32x4 __attribute__((ext_vector_type(4)));

__device__ __forceinline__ float bf2f(unsigned short h) {
  return __uint_as_float(((unsigned)h) << 16);
}
__device__ __forceinline__ unsigned short f2bf(float f) {
  unsigned u = __float_as_uint(f);
  u += 0x7FFF + ((u >> 16) & 1);   // round-to-nearest-even
  return (unsigned short)(u >> 16);
}

// erf via Abramowitz-Stegun 7.1.26, |abs err| < 1.5e-7
__device__ __forceinline__ float erf_fast(float x) {
  float ax = fabsf(x);
  float t = 1.0f / fmaf(0.3275911f, ax, 1.0f);
  float p = t * fmaf(t, fmaf(t, fmaf(t, fmaf(t, 1.061405429f, -1.453152027f),
                                     1.421413741f), -0.284496736f), 0.254829592f);
  float r = 1.0f - p * __expf(-ax * ax);
  return copysignf(r, x);
}
__device__ __forceinline__ float gelu_exact(float x) {
  return 0.5f * x * (1.0f + erf_fast(x * 0.70710678118654752f));
}

// reflect-shift source position: out[i] = x[i-s], reflect(-1)->1, reflect(32)->30
template <int AX>  // 0 none, 2=D, 3=H, 4=W
__device__ __forceinline__ int shift_src(int p, int s) {
  if (AX == 0) return p;
  const int SH = (AX == 4) ? 0 : (AX == 3) ? 5 : 10;
  int i = (p >> SH) & 31;
  int j = i - s;
  j = (j < 0) ? 1 : j;
  j = (j > 31) ? 30 : j;
  return p + ((j - i) << SH);
}

// LDS tile: [chunk c:3][pos p:64][ch-in-chunk u:64] bf16 (128B rows).
// 16B-granule swizzle g7 = (u>>3)^(p&7): compute-phase column reads and
// epilogue writes are 2-way (free).  SINGLE helper for all accesses (rule #21).
__device__ __forceinline__ int lds_off(int c, int p, int u) {
  return (c * 64 + p) * 128 + 16 * (((u >> 3) ^ (p & 7)) & 7) + 2 * (u & 7);
}

// One 192x64 GEMM accumulate: A = weights (global, L2-resident), B = LDS tile.
// SHIFTW: apply W-axis reflect-shift to B source positions at read time.
template <int SHIFTW>
__device__ __forceinline__ void do_gemm(const char* __restrict__ W,
                                        const unsigned short* __restrict__ wb,
                                        int wave, int col, int kg,
                                        f32x4 acc[3][4]) {
#pragma unroll
  for (int ks = 0; ks < 6; ++ks) {
    int k0 = ks * 32 + kg * 8;
    s16x8 af[3];
#pragma unroll
    for (int r = 0; r < 3; ++r)
      af[r] = *(const s16x8*)(wb + (wave * 48 + r * 16 + col) * NCH + k0);
    int c = k0 >> 6, u = k0 & 63;
    s16x8 bf[4];
#pragma unroll
    for (int m = 0; m < 4; ++m) {
      int p = m * 16 + col;
      int ps = SHIFTW ? shift_src<4>(p, c - 1) : p;
      bf[m] = *(const s16x8*)(W + lds_off(c, ps, u));
    }
#pragma unroll
    for (int r = 0; r < 3; ++r)
#pragma unroll
      for (int m = 0; m < 4; ++m)
        acc[r][m] = __builtin_amdgcn_mfma_f32_16x16x32_bf16(af[r], bf[m], acc[r][m], 0, 0, 0);
  }
}

// ---------------------------------------------------------------------------
// Unified pass kernel.
//   AX:    shift axis for the staging gather
//   EPI:   0 bias; 1 bias+stats; 2 bias+gelu+stats (applies to LAST gemm)
//   OUTF:  0 bf16 position-major (LDS round-trip store); 1 f32 channel-major
//   INF:   0 bf16 position-major (reg-prefetched when TPWk>1); 1 f32 ch-major
//   PERB:  per-sample weight/bias (K3 folded norm2)
//   FUSE:  gelu(v*A[ch]+C[ch]) in-register during staging (norm1+gelu)
//   TPWk:  tiles per WG (8 = pipelined with vr prefetch, 1 = simple)
//   CHAIN: two chained GEMMs (w,b then W-shift then w2,b2) per tile (K2b+K2c)
// ---------------------------------------------------------------------------
template <int AX, int EPI, int OUTF, int INF, int PERB, int FUSE, int TPWk, int CHAIN>
__global__ __launch_bounds__(256, 2)
void gemm_pass(const void* __restrict__ inv,
               const unsigned short* __restrict__ wmat,
               const float* __restrict__ bias,
               const unsigned short* __restrict__ wmat2,
               const float* __restrict__ bias2,
               void* __restrict__ outv,
               float* __restrict__ partials,
               const float* __restrict__ AC) {
  constexpr int NBUF = (TPWk > 1) ? 2 : 1;
  __shared__ __align__(16) char ldsW[NBUF][3 * 64 * 128];
  __shared__ __align__(16) char ldsT[CHAIN ? 3 * 64 * 128 : 16];
  __shared__ float acs[2 * NCH];
  __shared__ float red[4][2];

  constexpr int WGS_PER_B = TILES_ALL / TPWk;
  int wg = blockIdx.x;
  int b = wg / WGS_PER_B;
  int ti0 = (wg % WGS_PER_B) * TPWk;
  int tid = threadIdx.x;
  int wave = tid >> 6;
  int lane = tid & 63;
  int col = lane & 15;
  int kg = lane >> 4;

  const unsigned short* wbase = wmat + (PERB ? (size_t)b * NCH * NCH : 0);
  const float* bbase = bias + (PERB ? b * NCH : 0);
  const char* inbytes = (const char*)inv;
  const float* xin = (const float*)inv;
  float* outf = (float*)outv;

  if (FUSE) {
    for (int i = tid; i < 2 * NCH; i += 256) acs[i] = AC[b * 2 * NCH + i];
    __syncthreads();
  }

  // prefetch registers (INF==0 only): tile ti0
  s16x8 vr[6];
  if (INF == 0) {
#pragma unroll
    for (int j = 0; j < 6; ++j) {
      unsigned g = j * 256 + tid;
      int p = (int)(g / 24u), r24 = (int)(g - 24u * (unsigned)p);
      int ps = shift_src<AX>(ti0 * 64 + p, (r24 >> 3) - 1);
      vr[j] = *(const s16x8*)(inbytes + ((size_t)b * SPAT + ps) * 384 + r24 * 16);
    }
  }

  float ssum = 0.f, ssq = 0.f;

  for (int t = 0; t < TPWk; ++t) {
    char* W = ldsW[(NBUF == 2) ? (t & 1) : 0];
    int p0 = (ti0 + t) * 64;

    // ---- stage tile t into W ----
    if (INF == 1) {
      int c3 = tid >> 6, p = tid & 63;
      if (c3 < 3) {
        const float* src = xin + (size_t)b * NELEM_PER_B + (size_t)(c3 * 64) * SPAT + p0 + p;
#pragma unroll
        for (int j = 0; j < 8; ++j) {
          s16x8 v;
#pragma unroll
          for (int u = 0; u < 8; ++u)
            v[u] = (short)f2bf(src[(size_t)(8 * j + u) * SPAT]);
          *(s16x8*)(W + lds_off(c3, p, 8 * j)) = v;
        }
      }
    } else {
#pragma unroll
      for (int j = 0; j < 6; ++j) {
        unsigned g = j * 256 + tid;
        int p = (int)(g / 24u), r24 = (int)(g - 24u * (unsigned)p);
        s16x8 v = vr[j];
        if (FUSE) {
          int ch0 = r24 * 8;
#pragma unroll
          for (int u = 0; u < 8; ++u) {
            float f = bf2f((unsigned short)v[u]);
            f = fmaf(f, acs[ch0 + u], acs[NCH + ch0 + u]);
            f = gelu_exact(f);
            v[u] = (short)f2bf(f);
          }
        }
        *(s16x8*)(W + lds_off(r24 >> 3, p, (r24 & 7) * 8)) = v;
      }
      // ---- issue next tile's loads; they stay in flight across compute ----
      if (t + 1 < TPWk) {
        int p1 = (ti0 + t + 1) * 64;
#pragma unroll
        for (int j = 0; j < 6; ++j) {
          unsigned g = j * 256 + tid;
          int p = (int)(g / 24u), r24 = (int)(g - 24u * (unsigned)p);
          int ps = shift_src<AX>(p1 + p, (r24 >> 3) - 1);
          vr[j] = *(const s16x8*)(inbytes + ((size_t)b * SPAT + ps) * 384 + r24 * 16);
        }
      }
    }
    __syncthreads();   // B1: staged tile visible

    // ---- GEMM1 ----
    f32x4 acc[3][4] = {};
    do_gemm<0>(W, wbase, wave, col, kg, acc);

    if constexpr (CHAIN) {
      __syncthreads();   // B2: GEMM1's W-reads done; prev tile's T-reads long done
      // epi1: + bias -> T (bf16)
#pragma unroll
      for (int r = 0; r < 3; ++r) {
        int rowb = wave * 48 + r * 16 + kg * 4;
        f32x4 bs = *(const f32x4*)(bias + rowb);
#pragma unroll
        for (int m = 0; m < 4; ++m) {
          int p = m * 16 + col;
          uint2 pk;
          pk.x = (unsigned)f2bf(acc[r][m][0] + bs[0]) | ((unsigned)f2bf(acc[r][m][1] + bs[1]) << 16);
          pk.y = (unsigned)f2bf(acc[r][m][2] + bs[2]) | ((unsigned)f2bf(acc[r][m][3] + bs[3]) << 16);
          *(uint2*)(ldsT + lds_off(rowb >> 6, p, rowb & 63)) = pk;
        }
      }
      __syncthreads();   // B3: T visible
      // ---- GEMM2 with W-axis shift at read ----
#pragma unroll
      for (int r = 0; r < 3; ++r)
#pragma unroll
        for (int m = 0; m < 4; ++m) acc[r][m] = (f32x4){0.f, 0.f, 0.f, 0.f};
      do_gemm<1>(ldsT, wmat2, wave, col, kg, acc);
      // epi2: bias2 + gelu + stats -> W (W-reads done at B2; T-write next tile after B2')
#pragma unroll
      for (int r = 0; r < 3; ++r) {
        int rowb = wave * 48 + r * 16 + kg * 4;
        f32x4 bs = *(const f32x4*)(bias2 + rowb);
#pragma unroll
        for (int m = 0; m < 4; ++m) {
          int p = m * 16 + col;
          float v[4];
#pragma unroll
          for (int j = 0; j < 4; ++j) {
            float tv = acc[r][m][j] + bs[j];
            if (EPI == 2) tv = gelu_exact(tv);
            if (EPI >= 1) { ssum += tv; ssq = fmaf(tv, tv, ssq); }
            v[j] = tv;
          }
          uint2 pk;
          pk.x = (unsigned)f2bf(v[0]) | ((unsigned)f2bf(v[1]) << 16);
          pk.y = (unsigned)f2bf(v[2]) | ((unsigned)f2bf(v[3]) << 16);
          *(uint2*)(W + lds_off(rowb >> 6, p, rowb & 63)) = pk;
        }
      }
      __syncthreads();   // B4: W (output tile) visible
      char* outbytes = (char*)outv + ((size_t)b * SPAT + p0) * 384;
#pragma unroll
      for (int j = 0; j < 6; ++j) {
        unsigned g = j * 256 + tid;
        int p = (int)(g / 24u), r24 = (int)(g - 24u * (unsigned)p);
        s16x8 v = *(const s16x8*)(W + lds_off(r24 >> 3, p, (r24 & 7) * 8));
        *(s16x8*)(outbytes + g * 16) = v;
      }
    } else {
      // ---- single-GEMM epilogue ----
      if (OUTF == 0) __syncthreads();   // B2: W-reads done, reuse as out tile
#pragma unroll
      for (int r = 0; r < 3; ++r) {
        int rowb = wave * 48 + r * 16 + kg * 4;
        f32x4 bs = *(const f32x4*)(bbase + rowb);
#pragma unroll
        for (int m = 0; m < 4; ++m) {
          int p = m * 16 + col;
          float v[4];
#pragma unroll
          for (int j = 0; j < 4; ++j) {
            float tv = acc[r][m][j] + bs[j];
            if (EPI == 2) tv = gelu_exact(tv);
            if (EPI >= 1) { ssum += tv; ssq = fmaf(tv, tv, ssq); }
            v[j] = tv;
          }
          if (OUTF == 0) {
            uint2 pk;
            pk.x = (unsigned)f2bf(v[0]) | ((unsigned)f2bf(v[1]) << 16);
            pk.y = (unsigned)f2bf(v[2]) | ((unsigned)f2bf(v[3]) << 16);
            *(uint2*)(W + lds_off(rowb >> 6, p, rowb & 63)) = pk;
          } else {
#pragma unroll
            for (int j = 0; j < 4; ++j)
              outf[((size_t)b * NCH + rowb + j) * SPAT + p0 + p] = v[j];
          }
        }
      }
      if (OUTF == 0) {
        __syncthreads();   // B3: out tile visible
        char* outbytes = (char*)outv + ((size_t)b * SPAT + p0) * 384;
#pragma unroll
        for (int j = 0; j < 6; ++j) {
          unsigned g = j * 256 + tid;
          int p = (int)(g / 24u), r24 = (int)(g - 24u * (unsigned)p);
          s16x8 v = *(const s16x8*)(W + lds_off(r24 >> 3, p, (r24 & 7) * 8));
          *(s16x8*)(outbytes + g * 16) = v;
        }
      }
    }
  }

  if (EPI >= 1) {
#pragma unroll
    for (int off = 1; off < 64; off <<= 1) {
      ssum += __shfl_xor(ssum, off, 64);
      ssq += __shfl_xor(ssq, off, 64);
    }
    if (lane == 0) { red[wave][0] = ssum; red[wave][1] = ssq; }
    __syncthreads();
    if (tid == 0) {
      partials[wg * 2]     = red[0][0] + red[1][0] + red[2][0] + red[3][0];
      partials[wg * 2 + 1] = red[0][1] + red[1][1] + red[2][1] + red[3][1];
    }
  }
}

// Deterministic per-sample stats finalize: nper partials per sample
__global__ void stats_finalize(const float* __restrict__ partials,
                               const float* __restrict__ nw,
                               const float* __restrict__ nb,
                               float* __restrict__ AC, int nper) {
  int b = blockIdx.x;
  int tid = threadIdx.x;
  __shared__ float s0[256], s1[256];
  float a = 0.f, c = 0.f;
  for (int i = tid; i < nper; i += 256) {
    a += partials[(b * nper + i) * 2];
    c += partials[(b * nper + i) * 2 + 1];
  }
  s0[tid] = a; s1[tid] = c;
  __syncthreads();
  for (int st = 128; st > 0; st >>= 1) {
    if (tid < st) { s0[tid] += s0[tid + st]; s1[tid] += s1[tid + st]; }
    __syncthreads();
  }
  float inv_n = 1.0f / (float)(NELEM_PER_B);
  float mu = s0[0] * inv_n;
  float var = s1[0] * inv_n - mu * mu;
  float rs = rsqrtf(var + 1e-5f);
  if (tid < NCH) {
    float A = rs * nw[tid];
    AC[b * 2 * NCH + tid] = A;
    AC[b * 2 * NCH + NCH + tid] = nb[tid] - mu * A;
  }
}

// fp32 -> bf16 weight conversion: slots 0=w1, 1=w22, 2=w21, 3=w23
__global__ void prep_weights(const float* __restrict__ w1, const float* __restrict__ w21,
                             const float* __restrict__ w22, const float* __restrict__ w23,
                             unsigned short* __restrict__ wb) {
  int i = blockIdx.x * 256 + threadIdx.x;
  if (i >= 4 * NCH * NCH) return;
  int m = i / (NCH * NCH), r = i % (NCH * NCH);
  const float* src = (m == 0) ? w1 : (m == 1) ? w22 : (m == 2) ? w21 : w23;
  wb[i] = f2bf(src[r]);
}

// Fold norm2 affine into w3/b3 per sample
__global__ void prep_w3(const float* __restrict__ w3, const float* __restrict__ b3,
                        const float* __restrict__ AC2,
                        unsigned short* __restrict__ w3e, float* __restrict__ b3e) {
  int b = blockIdx.x;
  int o = threadIdx.x;
  if (o >= NCH) return;
  const float* A = AC2 + b * 2 * NCH;
  const float* C = A + NCH;
  float s = b3[o];
  for (int c = 0; c < NCH; ++c) {
    float w = w3[o * NCH + c];
    w3e[((size_t)b * NCH + o) * NCH + c] = f2bf(w * A[c]);
    s = fmaf(w, C[c], s);
  }
  b3e[b * NCH + o] = s;
}

extern "C" void kernel_launch(void* const* d_in, const int* in_sizes, int n_in,
                              void* d_out, int out_size, void* d_ws, size_t ws_size,
                              hipStream_t stream) {
  const float* x   = (const float*)d_in[0];
  const float* w1  = (const float*)d_in[1];
  const float* b1  = (const float*)d_in[2];
  const float* n1w = (const float*)d_in[3];
  const float* n1b = (const float*)d_in[4];
  const float* w21 = (const float*)d_in[5];
  const float* b21 = (const float*)d_in[6];
  const float* w22 = (const float*)d_in[7];
  const float* b22 = (const float*)d_in[8];
  const float* w23 = (const float*)d_in[9];
  const float* b23 = (const float*)d_in[10];
  const float* n2w = (const float*)d_in[11];
  const float* n2b = (const float*)d_in[12];
  const float* w3  = (const float*)d_in[13];
  const float* b3  = (const float*)d_in[14];

  char* ws = (char*)d_ws;
  size_t off = 0;
  unsigned short* wb = (unsigned short*)(ws + off); off += (size_t)4 * NCH * NCH * 2;
  off = (off + 255) & ~(size_t)255;
  unsigned short* w3e = (unsigned short*)(ws + off); off += (size_t)NB * NCH * NCH * 2;
  off = (off + 255) & ~(size_t)255;
  float* b3e = (float*)(ws + off); off += NB * NCH * 4;
  float* AC1 = (float*)(ws + off); off += NB * 2 * NCH * 4;
  float* AC2 = (float*)(ws + off); off += NB * 2 * NCH * 4;
  float* part1 = (float*)(ws + off); off += (size_t)NB * TILES_ALL * 2 * 4;
  float* part2 = (float*)(ws + off); off += 512 * 2 * 4;
  off = (off + 255) & ~(size_t)255;
  unsigned short* R1 = (unsigned short*)(ws + off);   // 100.7 MB bf16 scratch (ws)
  unsigned short* R2 = (unsigned short*)d_out;        // bf16 scratch in d_out space

  prep_weights<<<(4 * NCH * NCH + 255) / 256, 256, 0, stream>>>(w1, w21, w22, w23, wb);

  // K1: x (f32 cmajor) -> R1, W=w1, stats1.  TPW=1 (high-MLP transpose gather).
  gemm_pass<0, 1, 0, 1, 0, 0, 1, 0><<<NB * TILES_ALL, 256, 0, stream>>>(
      x, wb + 0 * NCH * NCH, b1, nullptr, nullptr, R1, part1, nullptr);
  stats_finalize<<<NB, 256, 0, stream>>>(part1, n1w, n1b, AC1, TILES_ALL);

  // K2a: fused norm1+gelu staging, shift H(3), W=w22: R1 -> R2.  Pipelined.
  gemm_pass<3, 0, 0, 0, 0, 1, 8, 0><<<512, 256, 0, stream>>>(
      R1, wb + 1 * NCH * NCH, b22, nullptr, nullptr, R2, nullptr, AC1);

  // K2bc: shift D(2) stage, GEMM(w21) -> T -> shiftW -> GEMM(w23), gelu+stats2.
  gemm_pass<2, 2, 0, 0, 0, 0, 8, 1><<<512, 256, 0, stream>>>(
      R2, wb + 2 * NCH * NCH, b21, wb + 3 * NCH * NCH, b23, R1, part2, nullptr);
  stats_finalize<<<NB, 256, 0, stream>>>(part2, n2w, n2b, AC2, 64);
  prep_w3<<<NB, NCH, 0, stream>>>(w3, b3, AC2, w3e, b3e);

  // K3: folded norm2 + conv3, f32 channel-major out: R1 -> d_out.  Pipelined.
  gemm_pass<0, 0, 1, 0, 1, 0, 8, 0><<<512, 256, 0, stream>>>(
      R1, w3e, b3e, nullptr, nullptr, d_out, nullptr, nullptr);
}